// Round 9
// baseline (270.110 us; speedup 1.0000x reference)
//
#include <hip/hip_runtime.h>
#include <stdint.h>

#define DI __device__ __forceinline__

typedef __attribute__((ext_vector_type(8))) short short8;
typedef __attribute__((ext_vector_type(4))) short short4v;
typedef __attribute__((ext_vector_type(4))) float float4v;
typedef __attribute__((ext_vector_type(2))) float float2v;
typedef __attribute__((ext_vector_type(4))) unsigned int uint4v;
typedef __attribute__((ext_vector_type(2))) unsigned int uint2v;
typedef __attribute__((ext_vector_type(2))) __bf16 bf162;

#define MFMA16(a, b, c) __builtin_amdgcn_mfma_f32_16x16x32_bf16((a), (b), (c), 0, 0, 0)

DI float b2f(short s) {
    uint32_t u = ((uint32_t)(uint16_t)s) << 16;
    float f;
    __builtin_memcpy(&f, &u, 4);
    return f;
}
// HW bf16 conversions (RTNE, pairs fuse to v_cvt_pk_bf16_f32)
DI unsigned int cvtpk(float a, float b) {
    bf162 h = __builtin_convertvector((float2v){a, b}, bf162);
    return __builtin_bit_cast(unsigned int, h);
}
DI float u2f(unsigned int u) { return __builtin_bit_cast(float, u); }

// B=64, C=2048, Q=128, D=128. Frag layout: frag_id*512 + lane*8 (+j), bf16.
// A/B frag mapping: row = tile*16 + (lane&15), col(k) = ks*32 + (lane>>4)*8 + j.

// Merged pack + small work. Grid (70, 64):
//   bx<64   : v-slab pack (nkc=64)
//   bx==64..67: q-slab pack (nkc=4, wm=w4mlu) [bx-64 = kc]
//   bx==68  : per-b pool (b = blockIdx.y)
//   bx==69  : weight packs (y 0..31 cqa_W, y 32..39 cc_W, rest idle)
__global__ __launch_bounds__(256) void k_packfuse(const float* __restrict__ vf, const float* __restrict__ qf,
                                                  const float* __restrict__ w4C, const float* __restrict__ w4Q,
                                                  const float* __restrict__ w4mlu, const float* __restrict__ vmask,
                                                  const float* __restrict__ qmask, short* __restrict__ vfA,
                                                  short* __restrict__ vfT, short* __restrict__ qfBW,
                                                  short* __restrict__ qTf, float* __restrict__ cvp,
                                                  float* __restrict__ qvp, const float* __restrict__ cqaW,
                                                  short* __restrict__ cqaWp, const float* __restrict__ ccW,
                                                  short* __restrict__ ccWp, const float* __restrict__ wp,
                                                  const float* __restrict__ ccb, float* __restrict__ pc) {
    __shared__ float St[32 * 133];
    __shared__ float Rd[128], Af[128], Pp[2][128], Pl[128];
    int bx = blockIdx.x, by = blockIdx.y;
    int t = threadIdx.x;
    if (bx == 69) {  // weight packs
        if (by < 32) {
            int idx = by * 256 + t;
            int lane = idx & 63, ks = (idx >> 6) & 3, part = (idx >> 8) & 3, nt = idx >> 10;
            const float* p = cqaW + (size_t)(nt * 16 + (lane & 15)) * 512 + part * 128 + ks * 32 + (lane >> 4) * 8;
            float4v a = *(const float4v*)p, b = *(const float4v*)(p + 4);
            uint4v ou;
            ou[0] = cvtpk(a[0], a[1]);
            ou[1] = cvtpk(a[2], a[3]);
            ou[2] = cvtpk(b[0], b[1]);
            ou[3] = cvtpk(b[2], b[3]);
            *(short8*)(cqaWp + (size_t)idx * 8) = __builtin_bit_cast(short8, ou);
        } else if (by < 40) {
            int idx = (by - 32) * 256 + t;
            int lane = idx & 63, ks = (idx >> 6) & 3, ot = idx >> 8;
            const float* p = ccW + (size_t)(ot * 16 + (lane & 15)) * 256 + ks * 32 + (lane >> 4) * 8;
            float4v a = *(const float4v*)p, b = *(const float4v*)(p + 4);
            uint4v ou;
            ou[0] = cvtpk(a[0], a[1]);
            ou[1] = cvtpk(a[2], a[3]);
            ou[2] = cvtpk(b[0], b[1]);
            ou[3] = cvtpk(b[2], b[3]);
            *(short8*)(ccWp + (size_t)idx * 8) = __builtin_bit_cast(short8, ou);
        }
        return;
    }
    if (bx == 68) {  // pool for b = by
        int b = by;
        int q = t >> 1, hf = t & 1;
        const float* qrow = qf + ((size_t)(b * 128 + q) << 7) + hf * 64;
        float s = 0.f;
#pragma unroll 4
        for (int d = 0; d < 64; d += 4) {
            float4v xv = *(const float4v*)(qrow + d);
            float4v wg = *(const float4v*)(wp + hf * 64 + d);
            s += xv[0] * wg[0] + xv[1] * wg[1] + xv[2] * wg[2] + xv[3] * wg[3];
        }
        s += __shfl_xor(s, 1, 64);
        s += (1.f - qmask[b * 128 + q]) * (-1e30f);
        if (hf == 0) Rd[q] = s;
        __syncthreads();
        for (int off = 64; off >= 1; off >>= 1) {
            if (t < off) Rd[t] = fmaxf(Rd[t], Rd[t + off]);
            __syncthreads();
        }
        float m = Rd[0];
        __syncthreads();
        float e = __expf(s - m);
        if (hf == 0) Rd[q] = e;
        __syncthreads();
        for (int off = 64; off >= 1; off >>= 1) {
            if (t < off) Rd[t] += Rd[t + off];
            __syncthreads();
        }
        if (hf == 0) Af[q] = e * __builtin_amdgcn_rcpf(Rd[0]);
        __syncthreads();
        {
            int d = t & 127, qh = t >> 7;
            float pacc = 0.f;
            for (int qq = qh * 64; qq < qh * 64 + 64; ++qq) pacc += qf[((size_t)(b * 128 + qq) << 7) + d] * Af[qq];
            Pp[qh][d] = pacc;
        }
        __syncthreads();
        if (t < 128) Pl[t] = Pp[0][t] + Pp[1][t];
        __syncthreads();
        {
            int o = t & 127, dh = t >> 7;
            float acc = 0.f;
            for (int d = dh * 64; d < dh * 64 + 64; ++d) acc += Pl[d] * ccW[o * 256 + 128 + d];
            Pp[dh][o] = acc;
        }
        __syncthreads();
        if (t < 128) pc[b * 128 + t] = ccb[t] + Pp[0][t] + Pp[1][t];
        return;
    }
    // ---- pack paths ----
    const float* src;
    const float* wm;
    const float* wv;
    const float* mask;
    short* dstA;
    short* dstT;
    float* dotout;
    int kc, nkc, b = by;
    if (bx < 64) {
        src = vf; wm = nullptr; wv = w4C; mask = vmask;
        dstA = vfA; dstT = vfT; dotout = cvp; kc = bx; nkc = 64;
    } else {
        src = qf; wm = w4mlu; wv = w4Q; mask = qmask;
        dstA = qfBW; dstT = qTf; dotout = qvp; kc = bx - 64; nkc = 4;
    }
    int rl = t >> 3, sub = t & 7, dseg = sub * 16;
    int grow = (b * nkc + kc) * 32 + rl;
    const float* p = src + ((size_t)grow << 7) + dseg;
    float4v v[4];
#pragma unroll
    for (int g = 0; g < 4; ++g) v[g] = *(const float4v*)(p + g * 4);
    // row-dot (raw values)
    float s = 0.f;
#pragma unroll
    for (int g = 0; g < 4; ++g) {
        float4v wg = *(const float4v*)(wv + dseg + g * 4);
#pragma unroll
        for (int j = 0; j < 4; ++j) s += v[g][j] * wg[j];
    }
#pragma unroll
    for (int off = 1; off < 8; off <<= 1) s += __shfl_xor(s, off, 64);
    if (sub == 0) dotout[grow] = s + (1.f - mask[grow]) * (-1e30f);
    // stage raw to LDS for transpose
#pragma unroll
    for (int g = 0; g < 4; ++g)
#pragma unroll
        for (int j = 0; j < 4; ++j) St[rl * 133 + dseg + g * 4 + j] = v[g][j];
    // A-frags (scaled by wm if given)
#pragma unroll
    for (int h = 0; h < 2; ++h) {
        int c16 = sub * 2 + h;
        int ks = c16 >> 2, quad = c16 & 3;
        float4v m0 = wm ? *(const float4v*)(wm + c16 * 8) : (float4v){1.f, 1.f, 1.f, 1.f};
        float4v m1 = wm ? *(const float4v*)(wm + c16 * 8 + 4) : (float4v){1.f, 1.f, 1.f, 1.f};
        uint4v ou;
        ou[0] = cvtpk(v[h * 2][0] * m0[0], v[h * 2][1] * m0[1]);
        ou[1] = cvtpk(v[h * 2][2] * m0[2], v[h * 2][3] * m0[3]);
        ou[2] = cvtpk(v[h * 2 + 1][0] * m1[0], v[h * 2 + 1][1] * m1[1]);
        ou[3] = cvtpk(v[h * 2 + 1][2] * m1[2], v[h * 2 + 1][3] * m1[3]);
        int tile = b * (nkc * 2) + kc * 2 + (rl >> 4);
        *(short8*)(dstA + ((size_t)(tile * 4 + ks) << 9) + (quad * 16 + (rl & 15)) * 8) =
            __builtin_bit_cast(short8, ou);
    }
    __syncthreads();
    // transposed B-frags
#pragma unroll
    for (int i = 0; i < 2; ++i) {
        int dt = (t >> 6) + i * 4;
        int lane = t & 63, ln = lane & 15, quad = lane >> 4;
        int d = dt * 16 + ln;
        uint4v ou;
#pragma unroll
        for (int wd = 0; wd < 4; ++wd)
            ou[wd] = cvtpk(St[(quad * 8 + 2 * wd) * 133 + d], St[(quad * 8 + 2 * wd + 1) * 133 + d]);
        *(short8*)(dstT + (((size_t)(b * 8 + dt) * nkc + kc) << 9) + lane * 8) = __builtin_bit_cast(short8, ou);
    }
}

// T^T partials over a C-half; deterministic fp32, no atomics. grid flat 1024 (XCD-swizzled).
// All 8 vfT B-frags hoisted to iteration top (latency hides under score+exp chain).
__global__ __launch_bounds__(256) void k_Tacc(const short* __restrict__ vfA, const short* __restrict__ vfT,
                                              const short* __restrict__ qfBW, const float* __restrict__ cvp,
                                              float* __restrict__ Pg, float* __restrict__ Csg) {
    __shared__ short Al[16 * 136];
    __shared__ float Red[4][16][130];
    __shared__ float csred[4][16];
    int tid = threadIdx.x, w = tid >> 6, lane = tid & 63, ln = lane & 15, quad = lane >> 4;
    // swizzle: keep all qt-blocks of one (b,s) on one XCD
    int id = blockIdx.x;
    int xcd = id & 7, k = id >> 3;
    int g = xcd * 16 + (k & 15);  // (b,s) group 0..127
    int qt = k >> 4;
    int b = g & 63, s = g >> 6;
    short8 bq[4];
#pragma unroll
    for (int ks = 0; ks < 4; ++ks) bq[ks] = *(const short8*)(qfBW + (((size_t)(b * 8 + qt) * 4 + ks) << 9) + lane * 8);
    float4v acc[8];
#pragma unroll
    for (int dt = 0; dt < 8; ++dt) acc[dt] = (float4v){0.f, 0.f, 0.f, 0.f};
    float colacc = 0.f;
    for (int it = 0; it < 8; ++it) {
        int cbase = s * 1024 + it * 128 + w * 32;
        int ct = b * 128 + (cbase >> 4);
        // hoist ALL 8 vfT B-frags; their latency hides under the score+exp chain
        short8 bb[8];
#pragma unroll
        for (int dt = 0; dt < 8; ++dt)
            bb[dt] = *(const short8*)(vfT + (((size_t)(b * 8 + dt) * 64 + s * 32 + it * 4 + w) << 9) + lane * 8);
        __builtin_amdgcn_sched_barrier(0);
        float4v ds[2];
        ds[0] = (float4v){0.f, 0.f, 0.f, 0.f};
        ds[1] = (float4v){0.f, 0.f, 0.f, 0.f};
#pragma unroll
        for (int ks = 0; ks < 4; ++ks) {
#pragma unroll
            for (int mt = 0; mt < 2; ++mt) {
                short8 a = *(const short8*)(vfA + (((size_t)(ct + mt) * 4 + ks) << 9) + lane * 8);
                ds[mt] = MFMA16(a, bq[ks], ds[mt]);
            }
        }
#pragma unroll
        for (int mt = 0; mt < 2; ++mt) {
            float4v cv = *(const float4v*)(cvp + b * 2048 + cbase + mt * 16 + quad * 4);
            float e0 = __expf(ds[mt][0] + cv[0]);
            float e1 = __expf(ds[mt][1] + cv[1]);
            float e2 = __expf(ds[mt][2] + cv[2]);
            float e3 = __expf(ds[mt][3] + cv[3]);
            colacc += e0 + e1 + e2 + e3;
            uint2v eu;
            eu[0] = cvtpk(e0, e1);
            eu[1] = cvtpk(e2, e3);
            *(short4v*)(Al + ln * 136 + w * 32 + mt * 16 + quad * 4) = __builtin_bit_cast(short4v, eu);
        }
        short8 a = *(const short8*)(Al + ln * 136 + w * 32 + quad * 8);
#pragma unroll
        for (int dt = 0; dt < 8; ++dt) acc[dt] = MFMA16(a, bb[dt], acc[dt]);
    }
#pragma unroll
    for (int dt = 0; dt < 8; ++dt)
#pragma unroll
        for (int r = 0; r < 4; ++r) Red[w][quad * 4 + r][dt * 16 + ln] = acc[dt][r];
    float p = colacc;
    p += __shfl_xor(p, 16, 64);
    p += __shfl_xor(p, 32, 64);
    if (lane < 16) csred[w][lane] = p;
    __syncthreads();
    if (tid < 16)
        Csg[((size_t)(s * 64 + b)) * 128 + qt * 16 + tid] =
            csred[0][tid] + csred[1][tid] + csred[2][tid] + csred[3][tid];
    {
        int q = tid >> 4, db = (tid & 15) * 8;
        float4v s0, s1;
#pragma unroll
        for (int j = 0; j < 4; ++j) {
            s0[j] = Red[0][q][db + j] + Red[1][q][db + j] + Red[2][q][db + j] + Red[3][q][db + j];
            s1[j] = Red[0][q][db + 4 + j] + Red[1][q][db + 4 + j] + Red[2][q][db + 4 + j] + Red[3][q][db + 4 + j];
        }
        size_t pb = (((size_t)(s * 64 + b)) * 8 + qt) * 2048 + q * 128 + db;
        *(float4v*)(Pg + pb) = s0;
        *(float4v*)(Pg + pb + 4) = s1;
    }
}

// Combine 2 partials + colsum -> Ttf bf16 B-frags.
__global__ __launch_bounds__(256) void k_Tcomb(const float* __restrict__ Pg, const float* __restrict__ Csg,
                                               short* __restrict__ Ttf) {
    int idx = blockIdx.x * 256 + threadIdx.x;  // 131072
    int lane = idx & 63, dt = (idx >> 8) & 7, b = idx >> 11;
    int d = dt * 16 + (lane & 15), q0 = ((idx >> 6) & 3) * 32 + (lane >> 4) * 8;
    float pv[8];
#pragma unroll
    for (int j = 0; j < 8; ++j) {
        int q = q0 + j;
        size_t o0 = ((size_t)(b * 8) + (q >> 4)) * 2048 + (q & 15) * 128 + d;
        size_t o1 = ((size_t)((64 + b) * 8) + (q >> 4)) * 2048 + (q & 15) * 128 + d;
        float cs = Csg[b * 128 + q] + Csg[(64 + b) * 128 + q];
        pv[j] = (Pg[o0] + Pg[o1]) * __builtin_amdgcn_rcpf(cs);
    }
    uint4v ou;
#pragma unroll
    for (int wd = 0; wd < 4; ++wd) ou[wd] = cvtpk(pv[2 * wd], pv[2 * wd + 1]);
    *(short8*)(Ttf + (size_t)idx * 8) = __builtin_bit_cast(short8, ou);
}

// Mega kernel. Phases 1-3 wave-private, cat/out N-split, frag-layout LDS.
// Cross-phase prefetch pinned with sched_barrier(0). grid flat 2048, 3 barriers.
__global__ __launch_bounds__(256, 4) void k_out(const short* __restrict__ vfA, const short* __restrict__ qfBW,
                                                const short* __restrict__ qTf, const short* __restrict__ Ttf,
                                                const float* __restrict__ qvp, const short* __restrict__ cqaWp,
                                                const float* __restrict__ cqab, const short* __restrict__ ccWp,
                                                const float* __restrict__ pc, float* __restrict__ out) {
    __shared__ __align__(16) short Sl[64 * 128];  // score_ -> q2c -> feats (frag layout)
    __shared__ __align__(16) short Xl[64 * 128];  // c2q (frag layout)
    int tid = threadIdx.x, w = tid >> 6, lane = tid & 63, ln = lane & 15, quad = lane >> 4;
    int jl = ln & 7, hi8 = ln >> 3;
    const float4v z4 = {0.f, 0.f, 0.f, 0.f};
    // swizzle: all c-tiles of one b on one XCD
    int id = blockIdx.x;
    int xcd = id & 7, k = id >> 3;
    int b = xcd * 8 + (k & 7);
    int cx = k >> 3;
    int c0 = cx * 64 + w * 16;
    int tt = b * 128 + (c0 >> 4);
    int wbase = w * 2048;
    // ---- phase 1: score tile 16c x 128q (A = raw v, B = w∘q) ----
    {
        float4v sc[8];
#pragma unroll
        for (int qt = 0; qt < 8; ++qt) sc[qt] = z4;
#pragma unroll
        for (int ks = 0; ks < 4; ++ks) {
            short8 bqf[8];
#pragma unroll
            for (int qt = 0; qt < 8; ++qt)
                bqf[qt] = *(const short8*)(qfBW + (((size_t)(b * 8 + qt) * 4 + ks) << 9) + lane * 8);
            short8 av = *(const short8*)(vfA + (((size_t)tt * 4 + ks) << 9) + lane * 8);
#pragma unroll
            for (int qt = 0; qt < 8; ++qt) sc[qt] = MFMA16(av, bqf[qt], sc[qt]);
        }
        float qvl[8];
#pragma unroll
        for (int qt = 0; qt < 8; ++qt) qvl[qt] = qvp[b * 128 + qt * 16 + ln];
        // prefetch phase-2 ks=0 B-frags; pin before the softmax VALU tail
        short8 p2[8];
#pragma unroll
        for (int dt = 0; dt < 8; ++dt)
            p2[dt] = *(const short8*)(qTf + (((size_t)(b * 8 + dt) * 4 + 0) << 9) + lane * 8);
        __builtin_amdgcn_sched_barrier(0);
        // ---- row softmax over q ----
#pragma unroll
        for (int r = 0; r < 4; ++r) {
            float x[8], m = -3.4e38f;
#pragma unroll
            for (int qt = 0; qt < 8; ++qt) {
                x[qt] = sc[qt][r] + qvl[qt];
                m = fmaxf(m, x[qt]);
            }
#pragma unroll
            for (int off = 1; off < 16; off <<= 1) m = fmaxf(m, __shfl_xor(m, off, 64));
            float e[8], sm = 0.f;
#pragma unroll
            for (int qt = 0; qt < 8; ++qt) {
                e[qt] = __expf(x[qt] - m);
                sm += e[qt];
            }
#pragma unroll
            for (int off = 1; off < 16; off <<= 1) sm += __shfl_xor(sm, off, 64);
            float inv = __builtin_amdgcn_rcpf(sm);
            int rb = (quad * 4 + r) * 8 + jl;  // (row-in-tile)*8 + j
#pragma unroll
            for (int qp = 0; qp < 4; ++qp) {
                unsigned int u = cvtpk(e[2 * qp] * inv, e[2 * qp + 1] * inv);
                Sl[wbase + qp * 512 + hi8 * 128 + rb] = (short)u;
                Sl[wbase + qp * 512 + (2 + hi8) * 128 + rb] = (short)(u >> 16);
            }
        }
        // ---- phase 2: c2q = score_ @ qf -> Xl ----
        short8 sa[4];  // score_ A-frags, reused by phase 3
#pragma unroll
        for (int ks = 0; ks < 4; ++ks) sa[ks] = *(const short8*)(Sl + wbase + ks * 512 + lane * 8);
        float4v a2q[8];
#pragma unroll
        for (int dt = 0; dt < 8; ++dt) a2q[dt] = MFMA16(sa[0], p2[dt], z4);
#pragma unroll
        for (int ks = 1; ks < 4; ++ks) {
            short8 bf[8];
#pragma unroll
            for (int dt = 0; dt < 8; ++dt)
                bf[dt] = *(const short8*)(qTf + (((size_t)(b * 8 + dt) * 4 + ks) << 9) + lane * 8);
#pragma unroll
            for (int dt = 0; dt < 8; ++dt) a2q[dt] = MFMA16(sa[ks], bf[dt], a2q[dt]);
        }
        // prefetch phase-3 ks=0 B-frags; pin before the cvt+LDS tail
        short8 p3[8];
#pragma unroll
        for (int dt = 0; dt < 8; ++dt)
            p3[dt] = *(const short8*)(Ttf + (((size_t)(b * 8 + dt) * 4 + 0) << 9) + lane * 8);
        __builtin_amdgcn_sched_barrier(0);
#pragma unroll
        for (int r = 0; r < 4; ++r) {
            int rb = (quad * 4 + r) * 8 + jl;
#pragma unroll
            for (int dp = 0; dp < 4; ++dp) {
                unsigned int u = cvtpk(a2q[2 * dp][r], a2q[2 * dp + 1][r]);
                Xl[wbase + dp * 512 + hi8 * 128 + rb] = (short)u;
                Xl[wbase + dp * 512 + (2 + hi8) * 128 + rb] = (short)(u >> 16);
            }
        }
        // ---- phase 3: q2c = score_ @ T -> Sl (sa[] in regs; Sl overwrite safe) ----
        float4v aq2[8];
#pragma unroll
        for (int dt = 0; dt < 8; ++dt) aq2[dt] = MFMA16(sa[0], p3[dt], z4);
#pragma unroll
        for (int ks = 1; ks < 4; ++ks) {
            short8 bf[8];
#pragma unroll
            for (int dt = 0; dt < 8; ++dt)
                bf[dt] = *(const short8*)(Ttf + (((size_t)(b * 8 + dt) * 4 + ks) << 9) + lane * 8);
#pragma unroll
            for (int dt = 0; dt < 8; ++dt) aq2[dt] = MFMA16(sa[ks], bf[dt], aq2[dt]);
        }
#pragma unroll
        for (int r = 0; r < 4; ++r) {
            int rb = (quad * 4 + r) * 8 + jl;
#pragma unroll
            for (int dp = 0; dp < 4; ++dp) {
                unsigned int u = cvtpk(aq2[2 * dp][r], aq2[2 * dp + 1][r]);
                Sl[wbase + dp * 512 + hi8 * 128 + rb] = (short)u;
                Sl[wbase + dp * 512 + (2 + hi8) * 128 + rb] = (short)(u >> 16);
            }
        }
    }
    __syncthreads();  // barrier1: Sl(q2c) + Xl(c2q) complete for all waves
    // ---- cat GEMM, N-split: wave w -> nt {2w, 2w+1}, all 64 c-rows ----
    float4v accF[4][2];
#pragma unroll
    for (int ct = 0; ct < 4; ++ct)
#pragma unroll
        for (int nt2 = 0; nt2 < 2; ++nt2) accF[ct][nt2] = z4;
#pragma unroll
    for (int ks = 0; ks < 4; ++ks) {
        short8 avk[4];
#pragma unroll
        for (int ct = 0; ct < 4; ++ct)
            avk[ct] = *(const short8*)(vfA + (((size_t)(b * 128 + cx * 4 + ct) * 4 + ks) << 9) + lane * 8);
#pragma unroll
        for (int part = 0; part < 4; ++part) {
            // weight frags first (hide load latency under the a[] VALU work)
            short8 bwp[2];
#pragma unroll
            for (int nt2 = 0; nt2 < 2; ++nt2)
                bwp[nt2] =
                    *(const short8*)(cqaWp + (((size_t)((w * 2 + nt2) * 4 + part) * 4 + ks) << 9) + lane * 8);
            short8 a[4];
#pragma unroll
            for (int ct = 0; ct < 4; ++ct) {
                int fo = ct * 2048 + ks * 512 + lane * 8;
                if (part == 0) {
                    a[ct] = avk[ct];
                } else if (part == 1) {
                    a[ct] = *(const short8*)(Xl + fo);
                } else {
                    short8 mfr = (part == 2) ? *(const short8*)(Xl + fo) : *(const short8*)(Sl + fo);
                    uint4v ua = __builtin_bit_cast(uint4v, avk[ct]);
                    uint4v um = __builtin_bit_cast(uint4v, mfr);
                    uint4v uo;
#pragma unroll
                    for (int wd = 0; wd < 4; ++wd) {
                        float a0 = u2f(ua[wd] << 16), a1 = u2f(ua[wd] & 0xffff0000u);
                        float m0 = u2f(um[wd] << 16), m1 = u2f(um[wd] & 0xffff0000u);
                        uo[wd] = cvtpk(a0 * m0, a1 * m1);
                    }
                    a[ct] = __builtin_bit_cast(short8, uo);
                }
            }
#pragma unroll
            for (int nt2 = 0; nt2 < 2; ++nt2)
#pragma unroll
                for (int ct = 0; ct < 4; ++ct) accF[ct][nt2] = MFMA16(a[ct], bwp[nt2], accF[ct][nt2]);
        }
    }
    __syncthreads();  // barrier2: all waves done reading Sl/Xl
    // ---- feats (+bias) -> Sl frag cols {w*32..w*32+31}, all tiles ----
    {
        float b0 = cqab[(w * 2) * 16 + ln], b1 = cqab[(w * 2 + 1) * 16 + ln];
#pragma unroll
        for (int ct = 0; ct < 4; ++ct)
#pragma unroll
            for (int r = 0; r < 4; ++r) {
                unsigned int u = cvtpk(accF[ct][0][r] + b0, accF[ct][1][r] + b1);
                int rb = ct * 2048 + w * 512 + (quad * 4 + r) * 8 + jl;
                Sl[rb + hi8 * 128] = (short)u;
                Sl[rb + (2 + hi8) * 128] = (short)(u >> 16);
            }
    }
    __syncthreads();  // barrier3: feats complete
    // ---- out = relu(feats @ ccW[:, :128].T + pc), N-split: wave w -> ot {2w, 2w+1} ----
    float4v accO[4][2];
#pragma unroll
    for (int ct = 0; ct < 4; ++ct)
#pragma unroll
        for (int ot2 = 0; ot2 < 2; ++ot2) accO[ct][ot2] = z4;
#pragma unroll
    for (int ks = 0; ks < 4; ++ks) {
        short8 bwo[2];
#pragma unroll
        for (int ot2 = 0; ot2 < 2; ++ot2)
            bwo[ot2] = *(const short8*)(ccWp + (((size_t)((w * 2 + ot2) * 4 + ks)) << 9) + lane * 8);
        short8 a[4];
#pragma unroll
        for (int ct = 0; ct < 4; ++ct) a[ct] = *(const short8*)(Sl + ct * 2048 + ks * 512 + lane * 8);
#pragma unroll
        for (int ot2 = 0; ot2 < 2; ++ot2)
#pragma unroll
            for (int ct = 0; ct < 4; ++ct) accO[ct][ot2] = MFMA16(a[ct], bwo[ot2], accO[ct][ot2]);
    }
#pragma unroll
    for (int ct = 0; ct < 4; ++ct)
#pragma unroll
        for (int ot2 = 0; ot2 < 2; ++ot2) {
            int o = (w * 2 + ot2) * 16 + ln;
            float pco = pc[b * 128 + o];
#pragma unroll
            for (int r = 0; r < 4; ++r) {
                int c = cx * 64 + ct * 16 + quad * 4 + r;
                out[((size_t)(b * 2048 + c) << 7) + o] = fmaxf(accO[ct][ot2][r] + pco, 0.f);
            }
        }
}

extern "C" void kernel_launch(void* const* d_in, const int* in_sizes, int n_in, void* d_out, int out_size, void* d_ws,
                              size_t ws_size, hipStream_t stream) {
    const float* vf = (const float*)d_in[0];
    const float* qf = (const float*)d_in[1];
    const float* vmask = (const float*)d_in[2];
    const float* qmask = (const float*)d_in[3];
    const float* w4C = (const float*)d_in[4];
    const float* w4Q = (const float*)d_in[5];
    const float* w4mlu = (const float*)d_in[6];
    const float* cqaW = (const float*)d_in[7];
    const float* cqab = (const float*)d_in[8];
    const float* wp = (const float*)d_in[9];
    const float* ccW = (const float*)d_in[10];
    const float* ccb = (const float*)d_in[11];
    float* out = (float*)d_out;
    char* ws = (char*)d_ws;

    // workspace layout (~83 MB)
    size_t o = 0;
    short* vfA = (short*)(ws + o); o += 64ull * 2048 * 128 * 2;   // 33.5 MB
    short* vfT = (short*)(ws + o); o += 64ull * 2048 * 128 * 2;   // 33.5 MB
    short* qfBW = (short*)(ws + o); o += 64ull * 128 * 128 * 2;   // 2 MB
    short* qTf = (short*)(ws + o); o += 64ull * 128 * 128 * 2;    // 2 MB
    short* Ttf = (short*)(ws + o); o += 64ull * 128 * 128 * 2;    // 2 MB
    short* cqaWp = (short*)(ws + o); o += 128ull * 512 * 2;       // 128 KB
    short* ccWp = (short*)(ws + o); o += 128ull * 128 * 2;        // 32 KB
    float* Pg = (float*)(ws + o); o += 2ull * 64 * 128 * 128 * 4; // 8.4 MB
    float* Csg = (float*)(ws + o); o += 2ull * 64 * 128 * 4;      // 64 KB
    float* cvp = (float*)(ws + o); o += 64ull * 2048 * 4;         // 512 KB
    float* qvp = (float*)(ws + o); o += 64ull * 128 * 4;
    float* pc = (float*)(ws + o); o += 64ull * 128 * 4;

    k_packfuse<<<dim3(70, 64), 256, 0, stream>>>(vf, qf, w4C, w4Q, w4mlu, vmask, qmask, vfA, vfT, qfBW, qTf, cvp,
                                                 qvp, cqaW, cqaWp, ccW, ccWp, wp, ccb, pc);
    k_Tacc<<<1024, 256, 0, stream>>>(vfA, vfT, qfBW, cvp, Pg, Csg);
    k_Tcomb<<<512, 256, 0, stream>>>(Pg, Csg, Ttf);
    k_out<<<2048, 256, 0, stream>>>(vfA, qfBW, qTf, Ttf, qvp, cqaWp, cqab, ccWp, pc, out);
}

// Round 10
// 251.341 us; speedup vs baseline: 1.0747x; 1.0747x over previous
//
#include <hip/hip_runtime.h>
#include <stdint.h>

#define DI __device__ __forceinline__

typedef __attribute__((ext_vector_type(8))) short short8;
typedef __attribute__((ext_vector_type(4))) short short4v;
typedef __attribute__((ext_vector_type(4))) float float4v;
typedef __attribute__((ext_vector_type(2))) float float2v;
typedef __attribute__((ext_vector_type(4))) unsigned int uint4v;
typedef __attribute__((ext_vector_type(2))) unsigned int uint2v;
typedef __attribute__((ext_vector_type(2))) __bf16 bf162;

#define MFMA16(a, b, c) __builtin_amdgcn_mfma_f32_16x16x32_bf16((a), (b), (c), 0, 0, 0)

DI float b2f(short s) {
    uint32_t u = ((uint32_t)(uint16_t)s) << 16;
    float f;
    __builtin_memcpy(&f, &u, 4);
    return f;
}
// HW bf16 conversions (RTNE, pairs fuse to v_cvt_pk_bf16_f32)
DI unsigned int cvtpk(float a, float b) {
    bf162 h = __builtin_convertvector((float2v){a, b}, bf162);
    return __builtin_bit_cast(unsigned int, h);
}
DI float u2f(unsigned int u) { return __builtin_bit_cast(float, u); }

// B=64, C=2048, Q=128, D=128. Frag layout: frag_id*512 + lane*8 (+j), bf16.
// A/B frag mapping: row = tile*16 + (lane&15), col(k) = ks*32 + (lane>>4)*8 + j.

// Merged pack + small work. Grid (70, 64):
//   bx<64   : v-slab pack (nkc=64)
//   bx==64..67: q-slab pack (nkc=4, wm=w4mlu) [bx-64 = kc]
//   bx==68  : per-b pool (b = blockIdx.y)
//   bx==69  : weight packs (y 0..31 cqa_W, y 32..39 cc_W, rest idle)
__global__ __launch_bounds__(256) void k_packfuse(const float* __restrict__ vf, const float* __restrict__ qf,
                                                  const float* __restrict__ w4C, const float* __restrict__ w4Q,
                                                  const float* __restrict__ w4mlu, const float* __restrict__ vmask,
                                                  const float* __restrict__ qmask, short* __restrict__ vfA,
                                                  short* __restrict__ vfT, short* __restrict__ qfBW,
                                                  short* __restrict__ qTf, float* __restrict__ cvp,
                                                  float* __restrict__ qvp, const float* __restrict__ cqaW,
                                                  short* __restrict__ cqaWp, const float* __restrict__ ccW,
                                                  short* __restrict__ ccWp, const float* __restrict__ wp,
                                                  const float* __restrict__ ccb, float* __restrict__ pc) {
    __shared__ float St[32 * 133];
    __shared__ float Rd[128], Af[128], Pp[2][128], Pl[128];
    int bx = blockIdx.x, by = blockIdx.y;
    int t = threadIdx.x;
    if (bx == 69) {  // weight packs
        if (by < 32) {
            int idx = by * 256 + t;
            int lane = idx & 63, ks = (idx >> 6) & 3, part = (idx >> 8) & 3, nt = idx >> 10;
            const float* p = cqaW + (size_t)(nt * 16 + (lane & 15)) * 512 + part * 128 + ks * 32 + (lane >> 4) * 8;
            float4v a = *(const float4v*)p, b = *(const float4v*)(p + 4);
            uint4v ou;
            ou[0] = cvtpk(a[0], a[1]);
            ou[1] = cvtpk(a[2], a[3]);
            ou[2] = cvtpk(b[0], b[1]);
            ou[3] = cvtpk(b[2], b[3]);
            *(short8*)(cqaWp + (size_t)idx * 8) = __builtin_bit_cast(short8, ou);
        } else if (by < 40) {
            int idx = (by - 32) * 256 + t;
            int lane = idx & 63, ks = (idx >> 6) & 3, ot = idx >> 8;
            const float* p = ccW + (size_t)(ot * 16 + (lane & 15)) * 256 + ks * 32 + (lane >> 4) * 8;
            float4v a = *(const float4v*)p, b = *(const float4v*)(p + 4);
            uint4v ou;
            ou[0] = cvtpk(a[0], a[1]);
            ou[1] = cvtpk(a[2], a[3]);
            ou[2] = cvtpk(b[0], b[1]);
            ou[3] = cvtpk(b[2], b[3]);
            *(short8*)(ccWp + (size_t)idx * 8) = __builtin_bit_cast(short8, ou);
        }
        return;
    }
    if (bx == 68) {  // pool for b = by
        int b = by;
        int q = t >> 1, hf = t & 1;
        const float* qrow = qf + ((size_t)(b * 128 + q) << 7) + hf * 64;
        float s = 0.f;
#pragma unroll 4
        for (int d = 0; d < 64; d += 4) {
            float4v xv = *(const float4v*)(qrow + d);
            float4v wg = *(const float4v*)(wp + hf * 64 + d);
            s += xv[0] * wg[0] + xv[1] * wg[1] + xv[2] * wg[2] + xv[3] * wg[3];
        }
        s += __shfl_xor(s, 1, 64);
        s += (1.f - qmask[b * 128 + q]) * (-1e30f);
        if (hf == 0) Rd[q] = s;
        __syncthreads();
        for (int off = 64; off >= 1; off >>= 1) {
            if (t < off) Rd[t] = fmaxf(Rd[t], Rd[t + off]);
            __syncthreads();
        }
        float m = Rd[0];
        __syncthreads();
        float e = __expf(s - m);
        if (hf == 0) Rd[q] = e;
        __syncthreads();
        for (int off = 64; off >= 1; off >>= 1) {
            if (t < off) Rd[t] += Rd[t + off];
            __syncthreads();
        }
        if (hf == 0) Af[q] = e * __builtin_amdgcn_rcpf(Rd[0]);
        __syncthreads();
        {
            int d = t & 127, qh = t >> 7;
            float pacc = 0.f;
            for (int qq = qh * 64; qq < qh * 64 + 64; ++qq) pacc += qf[((size_t)(b * 128 + qq) << 7) + d] * Af[qq];
            Pp[qh][d] = pacc;
        }
        __syncthreads();
        if (t < 128) Pl[t] = Pp[0][t] + Pp[1][t];
        __syncthreads();
        {
            int o = t & 127, dh = t >> 7;
            float acc = 0.f;
            for (int d = dh * 64; d < dh * 64 + 64; ++d) acc += Pl[d] * ccW[o * 256 + 128 + d];
            Pp[dh][o] = acc;
        }
        __syncthreads();
        if (t < 128) pc[b * 128 + t] = ccb[t] + Pp[0][t] + Pp[1][t];
        return;
    }
    // ---- pack paths ----
    const float* src;
    const float* wm;
    const float* wv;
    const float* mask;
    short* dstA;
    short* dstT;
    float* dotout;
    int kc, nkc, b = by;
    if (bx < 64) {
        src = vf; wm = nullptr; wv = w4C; mask = vmask;
        dstA = vfA; dstT = vfT; dotout = cvp; kc = bx; nkc = 64;
    } else {
        src = qf; wm = w4mlu; wv = w4Q; mask = qmask;
        dstA = qfBW; dstT = qTf; dotout = qvp; kc = bx - 64; nkc = 4;
    }
    int rl = t >> 3, sub = t & 7, dseg = sub * 16;
    int grow = (b * nkc + kc) * 32 + rl;
    const float* p = src + ((size_t)grow << 7) + dseg;
    float4v v[4];
#pragma unroll
    for (int g = 0; g < 4; ++g) v[g] = *(const float4v*)(p + g * 4);
    // row-dot (raw values)
    float s = 0.f;
#pragma unroll
    for (int g = 0; g < 4; ++g) {
        float4v wg = *(const float4v*)(wv + dseg + g * 4);
#pragma unroll
        for (int j = 0; j < 4; ++j) s += v[g][j] * wg[j];
    }
#pragma unroll
    for (int off = 1; off < 8; off <<= 1) s += __shfl_xor(s, off, 64);
    if (sub == 0) dotout[grow] = s + (1.f - mask[grow]) * (-1e30f);
    // stage raw to LDS for transpose
#pragma unroll
    for (int g = 0; g < 4; ++g)
#pragma unroll
        for (int j = 0; j < 4; ++j) St[rl * 133 + dseg + g * 4 + j] = v[g][j];
    // A-frags (scaled by wm if given)
#pragma unroll
    for (int h = 0; h < 2; ++h) {
        int c16 = sub * 2 + h;
        int ks = c16 >> 2, quad = c16 & 3;
        float4v m0 = wm ? *(const float4v*)(wm + c16 * 8) : (float4v){1.f, 1.f, 1.f, 1.f};
        float4v m1 = wm ? *(const float4v*)(wm + c16 * 8 + 4) : (float4v){1.f, 1.f, 1.f, 1.f};
        uint4v ou;
        ou[0] = cvtpk(v[h * 2][0] * m0[0], v[h * 2][1] * m0[1]);
        ou[1] = cvtpk(v[h * 2][2] * m0[2], v[h * 2][3] * m0[3]);
        ou[2] = cvtpk(v[h * 2 + 1][0] * m1[0], v[h * 2 + 1][1] * m1[1]);
        ou[3] = cvtpk(v[h * 2 + 1][2] * m1[2], v[h * 2 + 1][3] * m1[3]);
        int tile = b * (nkc * 2) + kc * 2 + (rl >> 4);
        *(short8*)(dstA + ((size_t)(tile * 4 + ks) << 9) + (quad * 16 + (rl & 15)) * 8) =
            __builtin_bit_cast(short8, ou);
    }
    __syncthreads();
    // transposed B-frags
#pragma unroll
    for (int i = 0; i < 2; ++i) {
        int dt = (t >> 6) + i * 4;
        int lane = t & 63, ln = lane & 15, quad = lane >> 4;
        int d = dt * 16 + ln;
        uint4v ou;
#pragma unroll
        for (int wd = 0; wd < 4; ++wd)
            ou[wd] = cvtpk(St[(quad * 8 + 2 * wd) * 133 + d], St[(quad * 8 + 2 * wd + 1) * 133 + d]);
        *(short8*)(dstT + (((size_t)(b * 8 + dt) * nkc + kc) << 9) + lane * 8) = __builtin_bit_cast(short8, ou);
    }
}

// T^T partials over a C-half; deterministic fp32, no atomics. grid flat 1024 (XCD-swizzled).
// bb[4] hoist (round-8-verified): 4 vfT B-frags prefetched + pinned; 4 loaded at tail.
// (bb[8] hoist regressed: +64 live VGPRs pushed past the 128 line -> occupancy cliff.)
__global__ __launch_bounds__(256) void k_Tacc(const short* __restrict__ vfA, const short* __restrict__ vfT,
                                              const short* __restrict__ qfBW, const float* __restrict__ cvp,
                                              float* __restrict__ Pg, float* __restrict__ Csg) {
    __shared__ short Al[16 * 136];
    __shared__ float Red[4][16][130];
    __shared__ float csred[4][16];
    int tid = threadIdx.x, w = tid >> 6, lane = tid & 63, ln = lane & 15, quad = lane >> 4;
    // swizzle: keep all qt-blocks of one (b,s) on one XCD
    int id = blockIdx.x;
    int xcd = id & 7, k = id >> 3;
    int g = xcd * 16 + (k & 15);  // (b,s) group 0..127
    int qt = k >> 4;
    int b = g & 63, s = g >> 6;
    short8 bq[4];
#pragma unroll
    for (int ks = 0; ks < 4; ++ks) bq[ks] = *(const short8*)(qfBW + (((size_t)(b * 8 + qt) * 4 + ks) << 9) + lane * 8);
    float4v acc[8];
#pragma unroll
    for (int dt = 0; dt < 8; ++dt) acc[dt] = (float4v){0.f, 0.f, 0.f, 0.f};
    float colacc = 0.f;
    for (int it = 0; it < 8; ++it) {
        int cbase = s * 1024 + it * 128 + w * 32;
        int ct = b * 128 + (cbase >> 4);
        // hoist half the vfT B-frags (independent of the score->exp->LDS chain)
        short8 bb[4];
#pragma unroll
        for (int dt = 0; dt < 4; ++dt)
            bb[dt] = *(const short8*)(vfT + (((size_t)(b * 8 + dt) * 64 + s * 32 + it * 4 + w) << 9) + lane * 8);
        __builtin_amdgcn_sched_barrier(0);
        float4v ds[2];
        ds[0] = (float4v){0.f, 0.f, 0.f, 0.f};
        ds[1] = (float4v){0.f, 0.f, 0.f, 0.f};
#pragma unroll
        for (int ks = 0; ks < 4; ++ks) {
#pragma unroll
            for (int mt = 0; mt < 2; ++mt) {
                short8 a = *(const short8*)(vfA + (((size_t)(ct + mt) * 4 + ks) << 9) + lane * 8);
                ds[mt] = MFMA16(a, bq[ks], ds[mt]);
            }
        }
#pragma unroll
        for (int mt = 0; mt < 2; ++mt) {
            float4v cv = *(const float4v*)(cvp + b * 2048 + cbase + mt * 16 + quad * 4);
            float e0 = __expf(ds[mt][0] + cv[0]);
            float e1 = __expf(ds[mt][1] + cv[1]);
            float e2 = __expf(ds[mt][2] + cv[2]);
            float e3 = __expf(ds[mt][3] + cv[3]);
            colacc += e0 + e1 + e2 + e3;
            uint2v eu;
            eu[0] = cvtpk(e0, e1);
            eu[1] = cvtpk(e2, e3);
            *(short4v*)(Al + ln * 136 + w * 32 + mt * 16 + quad * 4) = __builtin_bit_cast(short4v, eu);
        }
        short8 a = *(const short8*)(Al + ln * 136 + w * 32 + quad * 8);
#pragma unroll
        for (int dt = 0; dt < 4; ++dt) acc[dt] = MFMA16(a, bb[dt], acc[dt]);
#pragma unroll
        for (int dt = 4; dt < 8; ++dt) {
            short8 b2 = *(const short8*)(vfT + (((size_t)(b * 8 + dt) * 64 + s * 32 + it * 4 + w) << 9) + lane * 8);
            acc[dt] = MFMA16(a, b2, acc[dt]);
        }
    }
#pragma unroll
    for (int dt = 0; dt < 8; ++dt)
#pragma unroll
        for (int r = 0; r < 4; ++r) Red[w][quad * 4 + r][dt * 16 + ln] = acc[dt][r];
    float p = colacc;
    p += __shfl_xor(p, 16, 64);
    p += __shfl_xor(p, 32, 64);
    if (lane < 16) csred[w][lane] = p;
    __syncthreads();
    if (tid < 16)
        Csg[((size_t)(s * 64 + b)) * 128 + qt * 16 + tid] =
            csred[0][tid] + csred[1][tid] + csred[2][tid] + csred[3][tid];
    {
        int q = tid >> 4, db = (tid & 15) * 8;
        float4v s0, s1;
#pragma unroll
        for (int j = 0; j < 4; ++j) {
            s0[j] = Red[0][q][db + j] + Red[1][q][db + j] + Red[2][q][db + j] + Red[3][q][db + j];
            s1[j] = Red[0][q][db + 4 + j] + Red[1][q][db + 4 + j] + Red[2][q][db + 4 + j] + Red[3][q][db + 4 + j];
        }
        size_t pb = (((size_t)(s * 64 + b)) * 8 + qt) * 2048 + q * 128 + db;
        *(float4v*)(Pg + pb) = s0;
        *(float4v*)(Pg + pb + 4) = s1;
    }
}

// Combine 2 partials + colsum -> Ttf bf16 B-frags.
__global__ __launch_bounds__(256) void k_Tcomb(const float* __restrict__ Pg, const float* __restrict__ Csg,
                                               short* __restrict__ Ttf) {
    int idx = blockIdx.x * 256 + threadIdx.x;  // 131072
    int lane = idx & 63, dt = (idx >> 8) & 7, b = idx >> 11;
    int d = dt * 16 + (lane & 15), q0 = ((idx >> 6) & 3) * 32 + (lane >> 4) * 8;
    float pv[8];
#pragma unroll
    for (int j = 0; j < 8; ++j) {
        int q = q0 + j;
        size_t o0 = ((size_t)(b * 8) + (q >> 4)) * 2048 + (q & 15) * 128 + d;
        size_t o1 = ((size_t)((64 + b) * 8) + (q >> 4)) * 2048 + (q & 15) * 128 + d;
        float cs = Csg[b * 128 + q] + Csg[(64 + b) * 128 + q];
        pv[j] = (Pg[o0] + Pg[o1]) * __builtin_amdgcn_rcpf(cs);
    }
    uint4v ou;
#pragma unroll
    for (int wd = 0; wd < 4; ++wd) ou[wd] = cvtpk(pv[2 * wd], pv[2 * wd + 1]);
    *(short8*)(Ttf + (size_t)idx * 8) = __builtin_bit_cast(short8, ou);
}

// Mega kernel. Phases 1-3 wave-private, cat/out N-split, frag-layout LDS.
// Cross-phase prefetch pinned with sched_barrier(0). grid flat 2048, 3 barriers.
__global__ __launch_bounds__(256, 4) void k_out(const short* __restrict__ vfA, const short* __restrict__ qfBW,
                                                const short* __restrict__ qTf, const short* __restrict__ Ttf,
                                                const float* __restrict__ qvp, const short* __restrict__ cqaWp,
                                                const float* __restrict__ cqab, const short* __restrict__ ccWp,
                                                const float* __restrict__ pc, float* __restrict__ out) {
    __shared__ __align__(16) short Sl[64 * 128];  // score_ -> q2c -> feats (frag layout)
    __shared__ __align__(16) short Xl[64 * 128];  // c2q (frag layout)
    int tid = threadIdx.x, w = tid >> 6, lane = tid & 63, ln = lane & 15, quad = lane >> 4;
    int jl = ln & 7, hi8 = ln >> 3;
    const float4v z4 = {0.f, 0.f, 0.f, 0.f};
    // swizzle: all c-tiles of one b on one XCD
    int id = blockIdx.x;
    int xcd = id & 7, k = id >> 3;
    int b = xcd * 8 + (k & 7);
    int cx = k >> 3;
    int c0 = cx * 64 + w * 16;
    int tt = b * 128 + (c0 >> 4);
    int wbase = w * 2048;
    // ---- phase 1: score tile 16c x 128q (A = raw v, B = w∘q) ----
    {
        float4v sc[8];
#pragma unroll
        for (int qt = 0; qt < 8; ++qt) sc[qt] = z4;
#pragma unroll
        for (int ks = 0; ks < 4; ++ks) {
            short8 bqf[8];
#pragma unroll
            for (int qt = 0; qt < 8; ++qt)
                bqf[qt] = *(const short8*)(qfBW + (((size_t)(b * 8 + qt) * 4 + ks) << 9) + lane * 8);
            short8 av = *(const short8*)(vfA + (((size_t)tt * 4 + ks) << 9) + lane * 8);
#pragma unroll
            for (int qt = 0; qt < 8; ++qt) sc[qt] = MFMA16(av, bqf[qt], sc[qt]);
        }
        float qvl[8];
#pragma unroll
        for (int qt = 0; qt < 8; ++qt) qvl[qt] = qvp[b * 128 + qt * 16 + ln];
        // prefetch phase-2 ks=0 B-frags; pin before the softmax VALU tail
        short8 p2[8];
#pragma unroll
        for (int dt = 0; dt < 8; ++dt)
            p2[dt] = *(const short8*)(qTf + (((size_t)(b * 8 + dt) * 4 + 0) << 9) + lane * 8);
        __builtin_amdgcn_sched_barrier(0);
        // ---- row softmax over q ----
#pragma unroll
        for (int r = 0; r < 4; ++r) {
            float x[8], m = -3.4e38f;
#pragma unroll
            for (int qt = 0; qt < 8; ++qt) {
                x[qt] = sc[qt][r] + qvl[qt];
                m = fmaxf(m, x[qt]);
            }
#pragma unroll
            for (int off = 1; off < 16; off <<= 1) m = fmaxf(m, __shfl_xor(m, off, 64));
            float e[8], sm = 0.f;
#pragma unroll
            for (int qt = 0; qt < 8; ++qt) {
                e[qt] = __expf(x[qt] - m);
                sm += e[qt];
            }
#pragma unroll
            for (int off = 1; off < 16; off <<= 1) sm += __shfl_xor(sm, off, 64);
            float inv = __builtin_amdgcn_rcpf(sm);
            int rb = (quad * 4 + r) * 8 + jl;  // (row-in-tile)*8 + j
#pragma unroll
            for (int qp = 0; qp < 4; ++qp) {
                unsigned int u = cvtpk(e[2 * qp] * inv, e[2 * qp + 1] * inv);
                Sl[wbase + qp * 512 + hi8 * 128 + rb] = (short)u;
                Sl[wbase + qp * 512 + (2 + hi8) * 128 + rb] = (short)(u >> 16);
            }
        }
        // ---- phase 2: c2q = score_ @ qf -> Xl ----
        short8 sa[4];  // score_ A-frags, reused by phase 3
#pragma unroll
        for (int ks = 0; ks < 4; ++ks) sa[ks] = *(const short8*)(Sl + wbase + ks * 512 + lane * 8);
        float4v a2q[8];
#pragma unroll
        for (int dt = 0; dt < 8; ++dt) a2q[dt] = MFMA16(sa[0], p2[dt], z4);
#pragma unroll
        for (int ks = 1; ks < 4; ++ks) {
            short8 bf[8];
#pragma unroll
            for (int dt = 0; dt < 8; ++dt)
                bf[dt] = *(const short8*)(qTf + (((size_t)(b * 8 + dt) * 4 + ks) << 9) + lane * 8);
#pragma unroll
            for (int dt = 0; dt < 8; ++dt) a2q[dt] = MFMA16(sa[ks], bf[dt], a2q[dt]);
        }
        // prefetch phase-3 ks=0 B-frags; pin before the cvt+LDS tail
        short8 p3[8];
#pragma unroll
        for (int dt = 0; dt < 8; ++dt)
            p3[dt] = *(const short8*)(Ttf + (((size_t)(b * 8 + dt) * 4 + 0) << 9) + lane * 8);
        __builtin_amdgcn_sched_barrier(0);
#pragma unroll
        for (int r = 0; r < 4; ++r) {
            int rb = (quad * 4 + r) * 8 + jl;
#pragma unroll
            for (int dp = 0; dp < 4; ++dp) {
                unsigned int u = cvtpk(a2q[2 * dp][r], a2q[2 * dp + 1][r]);
                Xl[wbase + dp * 512 + hi8 * 128 + rb] = (short)u;
                Xl[wbase + dp * 512 + (2 + hi8) * 128 + rb] = (short)(u >> 16);
            }
        }
        // ---- phase 3: q2c = score_ @ T -> Sl (sa[] in regs; Sl overwrite safe) ----
        float4v aq2[8];
#pragma unroll
        for (int dt = 0; dt < 8; ++dt) aq2[dt] = MFMA16(sa[0], p3[dt], z4);
#pragma unroll
        for (int ks = 1; ks < 4; ++ks) {
            short8 bf[8];
#pragma unroll
            for (int dt = 0; dt < 8; ++dt)
                bf[dt] = *(const short8*)(Ttf + (((size_t)(b * 8 + dt) * 4 + ks) << 9) + lane * 8);
#pragma unroll
            for (int dt = 0; dt < 8; ++dt) aq2[dt] = MFMA16(sa[ks], bf[dt], aq2[dt]);
        }
#pragma unroll
        for (int r = 0; r < 4; ++r) {
            int rb = (quad * 4 + r) * 8 + jl;
#pragma unroll
            for (int dp = 0; dp < 4; ++dp) {
                unsigned int u = cvtpk(aq2[2 * dp][r], aq2[2 * dp + 1][r]);
                Sl[wbase + dp * 512 + hi8 * 128 + rb] = (short)u;
                Sl[wbase + dp * 512 + (2 + hi8) * 128 + rb] = (short)(u >> 16);
            }
        }
    }
    __syncthreads();  // barrier1: Sl(q2c) + Xl(c2q) complete for all waves
    // ---- cat GEMM, N-split: wave w -> nt {2w, 2w+1}, all 64 c-rows ----
    float4v accF[4][2];
#pragma unroll
    for (int ct = 0; ct < 4; ++ct)
#pragma unroll
        for (int nt2 = 0; nt2 < 2; ++nt2) accF[ct][nt2] = z4;
#pragma unroll
    for (int ks = 0; ks < 4; ++ks) {
        short8 avk[4];
#pragma unroll
        for (int ct = 0; ct < 4; ++ct)
            avk[ct] = *(const short8*)(vfA + (((size_t)(b * 128 + cx * 4 + ct) * 4 + ks) << 9) + lane * 8);
#pragma unroll
        for (int part = 0; part < 4; ++part) {
            // weight frags first (hide load latency under the a[] VALU work)
            short8 bwp[2];
#pragma unroll
            for (int nt2 = 0; nt2 < 2; ++nt2)
                bwp[nt2] =
                    *(const short8*)(cqaWp + (((size_t)((w * 2 + nt2) * 4 + part) * 4 + ks) << 9) + lane * 8);
            short8 a[4];
#pragma unroll
            for (int ct = 0; ct < 4; ++ct) {
                int fo = ct * 2048 + ks * 512 + lane * 8;
                if (part == 0) {
                    a[ct] = avk[ct];
                } else if (part == 1) {
                    a[ct] = *(const short8*)(Xl + fo);
                } else {
                    short8 mfr = (part == 2) ? *(const short8*)(Xl + fo) : *(const short8*)(Sl + fo);
                    uint4v ua = __builtin_bit_cast(uint4v, avk[ct]);
                    uint4v um = __builtin_bit_cast(uint4v, mfr);
                    uint4v uo;
#pragma unroll
                    for (int wd = 0; wd < 4; ++wd) {
                        float a0 = u2f(ua[wd] << 16), a1 = u2f(ua[wd] & 0xffff0000u);
                        float m0 = u2f(um[wd] << 16), m1 = u2f(um[wd] & 0xffff0000u);
                        uo[wd] = cvtpk(a0 * m0, a1 * m1);
                    }
                    a[ct] = __builtin_bit_cast(short8, uo);
                }
            }
#pragma unroll
            for (int nt2 = 0; nt2 < 2; ++nt2)
#pragma unroll
                for (int ct = 0; ct < 4; ++ct) accF[ct][nt2] = MFMA16(a[ct], bwp[nt2], accF[ct][nt2]);
        }
    }
    __syncthreads();  // barrier2: all waves done reading Sl/Xl
    // ---- feats (+bias) -> Sl frag cols {w*32..w*32+31}, all tiles ----
    {
        float b0 = cqab[(w * 2) * 16 + ln], b1 = cqab[(w * 2 + 1) * 16 + ln];
#pragma unroll
        for (int ct = 0; ct < 4; ++ct)
#pragma unroll
            for (int r = 0; r < 4; ++r) {
                unsigned int u = cvtpk(accF[ct][0][r] + b0, accF[ct][1][r] + b1);
                int rb = ct * 2048 + w * 512 + (quad * 4 + r) * 8 + jl;
                Sl[rb + hi8 * 128] = (short)u;
                Sl[rb + (2 + hi8) * 128] = (short)(u >> 16);
            }
    }
    __syncthreads();  // barrier3: feats complete
    // ---- out = relu(feats @ ccW[:, :128].T + pc), N-split: wave w -> ot {2w, 2w+1} ----
    float4v accO[4][2];
#pragma unroll
    for (int ct = 0; ct < 4; ++ct)
#pragma unroll
        for (int ot2 = 0; ot2 < 2; ++ot2) accO[ct][ot2] = z4;
#pragma unroll
    for (int ks = 0; ks < 4; ++ks) {
        short8 bwo[2];
#pragma unroll
        for (int ot2 = 0; ot2 < 2; ++ot2)
            bwo[ot2] = *(const short8*)(ccWp + (((size_t)((w * 2 + ot2) * 4 + ks)) << 9) + lane * 8);
        short8 a[4];
#pragma unroll
        for (int ct = 0; ct < 4; ++ct) a[ct] = *(const short8*)(Sl + ct * 2048 + ks * 512 + lane * 8);
#pragma unroll
        for (int ot2 = 0; ot2 < 2; ++ot2)
#pragma unroll
            for (int ct = 0; ct < 4; ++ct) accO[ct][ot2] = MFMA16(a[ct], bwo[ot2], accO[ct][ot2]);
    }
#pragma unroll
    for (int ct = 0; ct < 4; ++ct)
#pragma unroll
        for (int ot2 = 0; ot2 < 2; ++ot2) {
            int o = (w * 2 + ot2) * 16 + ln;
            float pco = pc[b * 128 + o];
#pragma unroll
            for (int r = 0; r < 4; ++r) {
                int c = cx * 64 + ct * 16 + quad * 4 + r;
                out[((size_t)(b * 2048 + c) << 7) + o] = fmaxf(accO[ct][ot2][r] + pco, 0.f);
            }
        }
}

extern "C" void kernel_launch(void* const* d_in, const int* in_sizes, int n_in, void* d_out, int out_size, void* d_ws,
                              size_t ws_size, hipStream_t stream) {
    const float* vf = (const float*)d_in[0];
    const float* qf = (const float*)d_in[1];
    const float* vmask = (const float*)d_in[2];
    const float* qmask = (const float*)d_in[3];
    const float* w4C = (const float*)d_in[4];
    const float* w4Q = (const float*)d_in[5];
    const float* w4mlu = (const float*)d_in[6];
    const float* cqaW = (const float*)d_in[7];
    const float* cqab = (const float*)d_in[8];
    const float* wp = (const float*)d_in[9];
    const float* ccW = (const float*)d_in[10];
    const float* ccb = (const float*)d_in[11];
    float* out = (float*)d_out;
    char* ws = (char*)d_ws;

    // workspace layout (~83 MB)
    size_t o = 0;
    short* vfA = (short*)(ws + o); o += 64ull * 2048 * 128 * 2;   // 33.5 MB
    short* vfT = (short*)(ws + o); o += 64ull * 2048 * 128 * 2;   // 33.5 MB
    short* qfBW = (short*)(ws + o); o += 64ull * 128 * 128 * 2;   // 2 MB
    short* qTf = (short*)(ws + o); o += 64ull * 128 * 128 * 2;    // 2 MB
    short* Ttf = (short*)(ws + o); o += 64ull * 128 * 128 * 2;    // 2 MB
    short* cqaWp = (short*)(ws + o); o += 128ull * 512 * 2;       // 128 KB
    short* ccWp = (short*)(ws + o); o += 128ull * 128 * 2;        // 32 KB
    float* Pg = (float*)(ws + o); o += 2ull * 64 * 128 * 128 * 4; // 8.4 MB
    float* Csg = (float*)(ws + o); o += 2ull * 64 * 128 * 4;      // 64 KB
    float* cvp = (float*)(ws + o); o += 64ull * 2048 * 4;         // 512 KB
    float* qvp = (float*)(ws + o); o += 64ull * 128 * 4;
    float* pc = (float*)(ws + o); o += 64ull * 128 * 4;

    k_packfuse<<<dim3(70, 64), 256, 0, stream>>>(vf, qf, w4C, w4Q, w4mlu, vmask, qmask, vfA, vfT, qfBW, qTf, cvp,
                                                 qvp, cqaW, cqaWp, ccW, ccWp, wp, ccb, pc);
    k_Tacc<<<1024, 256, 0, stream>>>(vfA, vfT, qfBW, cvp, Pg, Csg);
    k_Tcomb<<<512, 256, 0, stream>>>(Pg, Csg, Ttf);
    k_out<<<2048, 256, 0, stream>>>(vfA, qfBW, qTf, Ttf, qvp, cqaWp, cqab, ccWp, pc, out);
}